// Round 7
// baseline (4021.122 us; speedup 1.0000x reference)
//
#include <hip/hip_runtime.h>

#define D 128
#define RNUM 7
#define GNUM 64
#define LAYERS 3
#define NBA 8            // dest nodes per aggregation block
#define TM 64            // rows per transform block
#define SEG_SHIFT 3      // segments = node*8 + rel (slot 7 empty)

// ---------- x0[n,:] = emb[unit_type[n],:] ----------
__global__ __launch_bounds__(256) void init_x_kernel(const int* __restrict__ ut,
    const float* __restrict__ emb, float* __restrict__ x, int n) {
  int tid = blockIdx.x * 256 + threadIdx.x;
  int nidx = tid >> 5, q = tid & 31;
  if (nidx >= n) return;
  ((float4*)x)[(size_t)nidx * 32 + q] = ((const float4*)emb)[(size_t)ut[nidx] * 32 + q];
}

// ---------- CSR build: histogram over (dest node, rel) segments ----------
__global__ __launch_bounds__(256) void hist_kernel(const int* __restrict__ nout,
    const int* __restrict__ rel, int* __restrict__ hist, int ne) {
  int e = blockIdx.x * 256 + threadIdx.x;
  if (e >= ne) return;
  atomicAdd(&hist[(nout[e] << SEG_SHIFT) | rel[e]], 1);
}

// ---------- scan stage 1 ----------
__global__ __launch_bounds__(256) void scan1_kernel(const int* __restrict__ hist,
    int* __restrict__ row_ptr, int* __restrict__ partials, int nseg) {
  __shared__ int buf[256];
  const int t = threadIdx.x;
  const int base = blockIdx.x * 1024 + t * 4;
  int v0 = 0, v1 = 0, v2 = 0, v3 = 0;
  if (base + 3 < nseg) {
    int4 h4 = *(const int4*)&hist[base];
    v0 = h4.x; v1 = h4.y; v2 = h4.z; v3 = h4.w;
  } else {
    if (base + 0 < nseg) v0 = hist[base + 0];
    if (base + 1 < nseg) v1 = hist[base + 1];
    if (base + 2 < nseg) v2 = hist[base + 2];
    if (base + 3 < nseg) v3 = hist[base + 3];
  }
  int tsum = v0 + v1 + v2 + v3;
  buf[t] = tsum;
  __syncthreads();
  for (int off = 1; off < 256; off <<= 1) {
    int add = (t >= off) ? buf[t - off] : 0;
    __syncthreads();
    buf[t] += add;
    __syncthreads();
  }
  int incl = buf[t];
  int e0 = incl - tsum;
  int e1 = e0 + v0, e2 = e1 + v1, e3 = e2 + v2;
  if (base + 0 < nseg) row_ptr[base + 0] = e0;
  if (base + 1 < nseg) row_ptr[base + 1] = e1;
  if (base + 2 < nseg) row_ptr[base + 2] = e2;
  if (base + 3 < nseg) row_ptr[base + 3] = e3;
  if (t == 255) partials[blockIdx.x] = incl;
}

// ---------- scan stage 2 ----------
__global__ __launch_bounds__(256) void scan2_kernel(int* __restrict__ partials, int nb) {
  __shared__ int buf[256];
  __shared__ int carry_s;
  const int t = threadIdx.x;
  if (t == 0) carry_s = 0;
  __syncthreads();
  for (int c0 = 0; c0 < nb; c0 += 256) {
    int i = c0 + t;
    int v = (i < nb) ? partials[i] : 0;
    buf[t] = v;
    __syncthreads();
    for (int off = 1; off < 256; off <<= 1) {
      int add = (t >= off) ? buf[t - off] : 0;
      __syncthreads();
      buf[t] += add;
      __syncthreads();
    }
    int incl = buf[t];
    int excl = incl - v + carry_s;
    if (i < nb) partials[i] = excl;
    __syncthreads();
    if (t == 255) carry_s += incl;
    __syncthreads();
  }
}

// ---------- scan stage 3 ----------
__global__ __launch_bounds__(256) void scan3_kernel(int* __restrict__ row_ptr,
    int* __restrict__ cursor, const int* __restrict__ partials, int nseg, int ne) {
  int i = blockIdx.x * 256 + threadIdx.x;
  if (i < nseg) {
    int v = row_ptr[i] + partials[i >> 10];
    row_ptr[i] = v;
    cursor[i] = v;
  }
  if (i == 0) row_ptr[nseg] = ne;
}

// ---------- fill: (node_in | rel<<16 | dest_local<<19, ew) ----------
__global__ __launch_bounds__(256) void fill_kernel(const int* __restrict__ nin,
    const int* __restrict__ nout, const int* __restrict__ rel,
    const float* __restrict__ ew, int* __restrict__ cursor,
    int2* __restrict__ erec, int ne) {
  int e = blockIdx.x * 256 + threadIdx.x;
  if (e >= ne) return;
  int r = rel[e];
  int no = nout[e];
  int pos = atomicAdd(&cursor[(no << SEG_SHIFT) | r], 1);
  erec[pos] = make_int2(nin[e] | (r << 16) | ((no & (NBA - 1)) << 19),
                        __float_as_int(ew[e]));
}

__device__ __forceinline__ unsigned int pack_bf2(float a, float b) {
  unsigned int ua = __float_as_uint(a), ub = __float_as_uint(b);
  ua = (ua + 0x7FFFu + ((ua >> 16) & 1u)) >> 16;
  ub = (ub + 0x7FFFu + ((ub >> 16) & 1u)) >> 16;
  return ua | (ub << 16);
}

// ---------- edge-parallel aggregation ----------
// Block owns NBA=8 dest nodes + their contiguous CSR edge range.
// 8 independent 32-lane streams sweep disjoint sub-ranges: branch-free body
// (erec load -> x gather -> 4 LDS float atomics). Tile [dl][rel] padded to 8
// rels: 8*8*128 fp32 = 32 KB. Flushed once to global upd as bf16.
__global__ __launch_bounds__(256) void agg_kernel(
    const float* __restrict__ x, const int2* __restrict__ erec,
    const int* __restrict__ row_ptr, unsigned short* __restrict__ upd, int n) {
  __shared__ float acc_s[NBA * 8 * D];   // 32 KB
  const int t = threadIdx.x;
  const int b0 = blockIdx.x * NBA;
#pragma unroll
  for (int i = 0; i < 8; ++i)
    ((float4*)acc_s)[t + i * 256] = make_float4(0.f, 0.f, 0.f, 0.f);
  __syncthreads();

  int endn = b0 + NBA; if (endn > n) endn = n;
  const int es = row_ptr[b0 << SEG_SHIFT];
  const int ee = row_ptr[endn << SEG_SHIFT];
  const int cnt = ee - es;
  const int s = t >> 5;            // stream 0..7
  const int lane = t & 31;         // float4 lane
  const int chunk = (cnt + 7) >> 3;
  int e = es + s * chunk;
  int eend = e + chunk; if (eend > ee) eend = ee;
  const float4* X4 = (const float4*)x;

  for (; e < eend; ++e) {
    int2 rec = erec[e];
    float w = __int_as_float(rec.y);
    float4 v = X4[(size_t)(rec.x & 0xFFFF) * 32 + lane];
    float* dst = &acc_s[((rec.x >> 16) & 63) * D + lane * 4];
    atomicAdd(dst + 0, v.x * w);
    atomicAdd(dst + 1, v.y * w);
    atomicAdd(dst + 2, v.z * w);
    atomicAdd(dst + 3, v.w * w);
  }
  __syncthreads();

  // flush: NBA*896 = 7168 bf16 = 3584 uints, 14 per thread
  const int nvalid = endn - b0;
  unsigned int* upd32 = (unsigned int*)upd;
  const size_t ubase = (size_t)b0 * 448;   // *896/2
#pragma unroll
  for (int i = 0; i < 14; ++i) {
    int idx = t + i * 256;        // uint index in tile
    int p = idx * 2;              // elem index
    int node = p / 896;
    int within = p - node * 896;
    int rel = within >> 7, k = within & 127;
    if (node < nvalid) {
      float f0 = acc_s[((node << 3) | rel) * D + k];
      float f1 = acc_s[((node << 3) | rel) * D + k + 1];
      upd32[ubase + idx] = pack_bf2(f0, f1);
    }
  }
}

__device__ __forceinline__ void fma4(float4& d, float s, const float4& v) {
  d.x += s * v.x; d.y += s * v.y; d.z += s * v.z; d.w += s * v.w;
}

// ---------- transform GEMM ----------
// h[m,:] = relu( upd(bf16, K=896)@Wrel + x(fp32, K=128)@Wloop + brel + bloop )
// 64-row tile, 256 threads: thread (tc 0..31 cols-as-float4, tr 0..7 rows*8),
// A chunks (64x64) staged to fp32 LDS; round-1's conflict-free inner loop.
__global__ __launch_bounds__(256) void xform_kernel(
    const unsigned short* __restrict__ upd, const float* __restrict__ x,
    const float* __restrict__ Wrel, const float* __restrict__ brel,
    const float* __restrict__ Wloop, const float* __restrict__ bloop,
    float* __restrict__ h, int n) {
  __shared__ float As[TM * 64];    // 16 KB
  const int t = threadIdx.x;
  const int m0 = blockIdx.x * TM;
  const int tc = t & 31, tr = t >> 5;
  const int srow = t >> 2;               // staging row 0..63
  const int sks = (t & 3) * 16;          // staging k-offset
  const int sgrow = m0 + srow;
  float4* As4 = (float4*)As;

  float4 acc[8];
#pragma unroll
  for (int i = 0; i < 8; ++i) acc[i] = make_float4(0.f, 0.f, 0.f, 0.f);

  const float4* Wr4 = (const float4*)Wrel;    // 896 x 32 float4
  // --- K = 896 over bf16 upd ---
  for (int kc = 0; kc < RNUM * D; kc += 64) {
    // stage 64x64 bf16 -> fp32 LDS
    uint4 p0 = make_uint4(0, 0, 0, 0), p1 = p0;
    if (sgrow < n) {
      const uint4* src = (const uint4*)(upd + (size_t)sgrow * 896 + kc + sks);
      p0 = src[0]; p1 = src[1];
    }
    float4 f0, f1, f2, f3;
    f0.x = __uint_as_float(p0.x << 16); f0.y = __uint_as_float(p0.x & 0xFFFF0000u);
    f0.z = __uint_as_float(p0.y << 16); f0.w = __uint_as_float(p0.y & 0xFFFF0000u);
    f1.x = __uint_as_float(p0.z << 16); f1.y = __uint_as_float(p0.z & 0xFFFF0000u);
    f1.z = __uint_as_float(p0.w << 16); f1.w = __uint_as_float(p0.w & 0xFFFF0000u);
    f2.x = __uint_as_float(p1.x << 16); f2.y = __uint_as_float(p1.x & 0xFFFF0000u);
    f2.z = __uint_as_float(p1.y << 16); f2.w = __uint_as_float(p1.y & 0xFFFF0000u);
    f3.x = __uint_as_float(p1.z << 16); f3.y = __uint_as_float(p1.z & 0xFFFF0000u);
    f3.z = __uint_as_float(p1.w << 16); f3.w = __uint_as_float(p1.w & 0xFFFF0000u);
    int sb = (srow * 64 + sks) >> 2;
    As4[sb + 0] = f0; As4[sb + 1] = f1; As4[sb + 2] = f2; As4[sb + 3] = f3;
    __syncthreads();

    for (int k = 0; k < 64; k += 4) {
      float4 a[8];
#pragma unroll
      for (int i = 0; i < 8; ++i)
        a[i] = As4[(tr * 8 + i) * 16 + (k >> 2)];
#pragma unroll
      for (int kk = 0; kk < 4; ++kk) {
        float4 w = Wr4[(size_t)(kc + k + kk) * 32 + tc];
#pragma unroll
        for (int i = 0; i < 8; ++i) {
          float av = (kk == 0) ? a[i].x : (kk == 1) ? a[i].y : (kk == 2) ? a[i].z : a[i].w;
          fma4(acc[i], av, w);
        }
      }
    }
    __syncthreads();
  }

  // --- K = 128 over fp32 x (self-loop) ---
  const float4* X4 = (const float4*)x;
  const float4* Wl4 = (const float4*)Wloop;   // 128 x 32 float4
  for (int kc = 0; kc < D; kc += 64) {
    float4 g0 = make_float4(0, 0, 0, 0), g1 = g0, g2 = g0, g3 = g0;
    if (sgrow < n) {
      const float4* src = &X4[(size_t)sgrow * 32 + ((kc + sks) >> 2)];
      g0 = src[0]; g1 = src[1]; g2 = src[2]; g3 = src[3];
    }
    int sb = (srow * 64 + sks) >> 2;
    As4[sb + 0] = g0; As4[sb + 1] = g1; As4[sb + 2] = g2; As4[sb + 3] = g3;
    __syncthreads();

    for (int k = 0; k < 64; k += 4) {
      float4 a[8];
#pragma unroll
      for (int i = 0; i < 8; ++i)
        a[i] = As4[(tr * 8 + i) * 16 + (k >> 2)];
#pragma unroll
      for (int kk = 0; kk < 4; ++kk) {
        float4 w = Wl4[(size_t)(kc + k + kk) * 32 + tc];
#pragma unroll
        for (int i = 0; i < 8; ++i) {
          float av = (kk == 0) ? a[i].x : (kk == 1) ? a[i].y : (kk == 2) ? a[i].z : a[i].w;
          fma4(acc[i], av, w);
        }
      }
    }
    __syncthreads();
  }

  float4 br = ((const float4*)brel)[tc];
  float4 bl = ((const float4*)bloop)[tc];
  float4 bias = make_float4(br.x + bl.x, br.y + bl.y, br.z + bl.z, br.w + bl.w);
#pragma unroll
  for (int i = 0; i < 8; ++i) {
    int grow = m0 + tr * 8 + i;
    if (grow < n) {
      float4 o;
      o.x = fmaxf(acc[i].x + bias.x, 0.f);
      o.y = fmaxf(acc[i].y + bias.y, 0.f);
      o.z = fmaxf(acc[i].z + bias.z, 0.f);
      o.w = fmaxf(acc[i].w + bias.w, 0.f);
      ((float4*)h)[(size_t)grow * 32 + tc] = o;
    }
  }
}

// ---------- graph pooling (node2graph sorted) ----------
__global__ __launch_bounds__(256) void pool_kernel(const float* __restrict__ x,
    const int* __restrict__ n2g, float* __restrict__ gf, int n) {
  int d = threadIdx.x & 127;
  int sub = threadIdx.x >> 7;
  int n0 = (blockIdx.x * 2 + sub) * 128;
  int nend = n0 + 128;
  if (nend > n) nend = n;
  float acc = 0.f;
  int gcur = -1;
  for (int i = n0; i < nend; ++i) {
    int g = n2g[i];
    if (g != gcur) {
      if (gcur >= 0) atomicAdd(&gf[gcur * D + d], acc);
      gcur = g;
      acc = 0.f;
    }
    acc += x[(size_t)i * D + d];
  }
  if (gcur >= 0) atomicAdd(&gf[gcur * D + d], acc);
}

extern "C" void kernel_launch(void* const* d_in, const int* in_sizes, int n_in,
                              void* d_out, int out_size, void* d_ws, size_t ws_size,
                              hipStream_t stream) {
  const int*   unit_type  = (const int*)d_in[0];
  const int*   node_in    = (const int*)d_in[1];
  const int*   node_out   = (const int*)d_in[2];
  const int*   relation   = (const int*)d_in[3];
  const float* edge_w     = (const float*)d_in[4];
  const int*   node2graph = (const int*)d_in[5];
  const float* emb        = (const float*)d_in[6];
  const float* W_rel      = (const float*)d_in[7];
  const float* b_rel      = (const float*)d_in[8];
  const float* W_loop     = (const float*)d_in[9];
  const float* b_loop     = (const float*)d_in[10];

  const int n  = in_sizes[0];
  const int ne = in_sizes[1];
  float* out = (float*)d_out;

  const int nseg = n << SEG_SHIFT;
  const int nb   = (nseg + 1023) / 1024;

  // workspace layout
  const size_t ND = (size_t)n * D;
  float*          x0       = (float*)d_ws;
  float*          x1       = x0 + ND;
  unsigned short* upd      = (unsigned short*)(x1 + ND);       // N*896 bf16
  int2*           erec     = (int2*)(upd + (size_t)n * RNUM * D);
  int*            hist     = (int*)(erec + ne);
  int*            row_ptr  = hist + nseg;
  int*            cursor   = row_ptr + ((nseg + 4) & ~3);
  int*            partials = cursor + nseg;

  hipMemsetAsync(d_out, 0, (size_t)GNUM * D * sizeof(float), stream);
  hipMemsetAsync(hist, 0, (size_t)nseg * sizeof(int), stream);

  const int eblocks = (ne + 255) / 256;
  hist_kernel<<<eblocks, 256, 0, stream>>>(node_out, relation, hist, ne);
  scan1_kernel<<<nb, 256, 0, stream>>>(hist, row_ptr, partials, nseg);
  scan2_kernel<<<1, 256, 0, stream>>>(partials, nb);
  scan3_kernel<<<(nseg + 255) / 256, 256, 0, stream>>>(row_ptr, cursor, partials, nseg, ne);
  fill_kernel<<<eblocks, 256, 0, stream>>>(node_in, node_out, relation, edge_w,
                                           cursor, erec, ne);

  const int nq = n * 32;
  init_x_kernel<<<(nq + 255) / 256, 256, 0, stream>>>(unit_type, emb, x0, n);

  const int ablocks = (n + NBA - 1) / NBA;
  const int tblocks = (n + TM - 1) / TM;
  float* cur = x0;
  for (int i = 0; i < LAYERS; ++i) {
    float* nxt = (i == LAYERS - 1) ? (out + GNUM * D) : (cur == x0 ? x1 : x0);
    agg_kernel<<<ablocks, 256, 0, stream>>>(cur, erec, row_ptr, upd, n);
    xform_kernel<<<tblocks, 256, 0, stream>>>(
        upd, cur,
        W_rel + (size_t)i * RNUM * D * D, b_rel + (size_t)i * D,
        W_loop + (size_t)i * D * D, b_loop + (size_t)i * D,
        nxt, n);
    cur = nxt;
  }

  pool_kernel<<<(n + 255) / 256, 256, 0, stream>>>(cur, node2graph, out, n);
}

// Round 8
// 1366.688 us; speedup vs baseline: 2.9422x; 2.9422x over previous
//
#include <hip/hip_runtime.h>

#define D 128
#define RNUM 7
#define GNUM 64
#define LAYERS 3
#define NBA 8            // dest nodes per aggregation block
#define TM 64            // rows per transform block
#define SEG_SHIFT 3      // segments = node*8 + rel (slot 7 empty)

// ---------- x0[n,:] = emb[unit_type[n],:] ----------
__global__ __launch_bounds__(256) void init_x_kernel(const int* __restrict__ ut,
    const float* __restrict__ emb, float* __restrict__ x, int n) {
  int tid = blockIdx.x * 256 + threadIdx.x;
  int nidx = tid >> 5, q = tid & 31;
  if (nidx >= n) return;
  ((float4*)x)[(size_t)nidx * 32 + q] = ((const float4*)emb)[(size_t)ut[nidx] * 32 + q];
}

// ---------- CSR build: histogram over (dest node, rel) segments ----------
__global__ __launch_bounds__(256) void hist_kernel(const int* __restrict__ nout,
    const int* __restrict__ rel, int* __restrict__ hist, int ne) {
  int e = blockIdx.x * 256 + threadIdx.x;
  if (e >= ne) return;
  atomicAdd(&hist[(nout[e] << SEG_SHIFT) | rel[e]], 1);
}

// ---------- scan stage 1 ----------
__global__ __launch_bounds__(256) void scan1_kernel(const int* __restrict__ hist,
    int* __restrict__ row_ptr, int* __restrict__ partials, int nseg) {
  __shared__ int buf[256];
  const int t = threadIdx.x;
  const int base = blockIdx.x * 1024 + t * 4;
  int v0 = 0, v1 = 0, v2 = 0, v3 = 0;
  if (base + 3 < nseg) {
    int4 h4 = *(const int4*)&hist[base];
    v0 = h4.x; v1 = h4.y; v2 = h4.z; v3 = h4.w;
  } else {
    if (base + 0 < nseg) v0 = hist[base + 0];
    if (base + 1 < nseg) v1 = hist[base + 1];
    if (base + 2 < nseg) v2 = hist[base + 2];
    if (base + 3 < nseg) v3 = hist[base + 3];
  }
  int tsum = v0 + v1 + v2 + v3;
  buf[t] = tsum;
  __syncthreads();
  for (int off = 1; off < 256; off <<= 1) {
    int add = (t >= off) ? buf[t - off] : 0;
    __syncthreads();
    buf[t] += add;
    __syncthreads();
  }
  int incl = buf[t];
  int e0 = incl - tsum;
  int e1 = e0 + v0, e2 = e1 + v1, e3 = e2 + v2;
  if (base + 0 < nseg) row_ptr[base + 0] = e0;
  if (base + 1 < nseg) row_ptr[base + 1] = e1;
  if (base + 2 < nseg) row_ptr[base + 2] = e2;
  if (base + 3 < nseg) row_ptr[base + 3] = e3;
  if (t == 255) partials[blockIdx.x] = incl;
}

// ---------- scan stage 2 ----------
__global__ __launch_bounds__(256) void scan2_kernel(int* __restrict__ partials, int nb) {
  __shared__ int buf[256];
  __shared__ int carry_s;
  const int t = threadIdx.x;
  if (t == 0) carry_s = 0;
  __syncthreads();
  for (int c0 = 0; c0 < nb; c0 += 256) {
    int i = c0 + t;
    int v = (i < nb) ? partials[i] : 0;
    buf[t] = v;
    __syncthreads();
    for (int off = 1; off < 256; off <<= 1) {
      int add = (t >= off) ? buf[t - off] : 0;
      __syncthreads();
      buf[t] += add;
      __syncthreads();
    }
    int incl = buf[t];
    int excl = incl - v + carry_s;
    if (i < nb) partials[i] = excl;
    __syncthreads();
    if (t == 255) carry_s += incl;
    __syncthreads();
  }
}

// ---------- scan stage 3 ----------
__global__ __launch_bounds__(256) void scan3_kernel(int* __restrict__ row_ptr,
    int* __restrict__ cursor, const int* __restrict__ partials, int nseg, int ne) {
  int i = blockIdx.x * 256 + threadIdx.x;
  if (i < nseg) {
    int v = row_ptr[i] + partials[i >> 10];
    row_ptr[i] = v;
    cursor[i] = v;
  }
  if (i == 0) row_ptr[nseg] = ne;
}

// ---------- fill: (node_in | rel<<16 | dest_local<<19, ew) ----------
__global__ __launch_bounds__(256) void fill_kernel(const int* __restrict__ nin,
    const int* __restrict__ nout, const int* __restrict__ rel,
    const float* __restrict__ ew, int* __restrict__ cursor,
    int2* __restrict__ erec, int ne) {
  int e = blockIdx.x * 256 + threadIdx.x;
  if (e >= ne) return;
  int r = rel[e];
  int no = nout[e];
  int pos = atomicAdd(&cursor[(no << SEG_SHIFT) | r], 1);
  erec[pos] = make_int2(nin[e] | (r << 16) | ((no & (NBA - 1)) << 19),
                        __float_as_int(ew[e]));
}

__device__ __forceinline__ unsigned int pack_bf2(float a, float b) {
  unsigned int ua = __float_as_uint(a), ub = __float_as_uint(b);
  ua = (ua + 0x7FFFu + ((ua >> 16) & 1u)) >> 16;
  ub = (ub + 0x7FFFu + ((ub >> 16) & 1u)) >> 16;
  return ua | (ub << 16);
}

__device__ __forceinline__ void fma4(float4& d, float s, const float4& v) {
  d.x += s * v.x; d.y += s * v.y; d.z += s * v.z; d.w += s * v.w;
}

// ---------- edge-parallel aggregation, register segmented-sum ----------
// Block owns NBA=8 dest nodes + their contiguous (node,rel)-sorted edge range.
// 8 streams of 32 lanes sweep disjoint quotas with ONE running float4 acc;
// flush on segment change: interior segment -> plain LDS float4 store (stream
// owns whole segment; row==segment so no races), stream's first/last segment
// (possibly shared with neighbor stream) -> LDS atomicAdd (rare, <=16/block).
__global__ __launch_bounds__(256) void agg_kernel(
    const float* __restrict__ x, const int2* __restrict__ erec,
    const int* __restrict__ row_ptr, unsigned short* __restrict__ upd, int n) {
  __shared__ float acc_s[NBA * 8 * D];   // 32 KB
  const int t = threadIdx.x;
  const int b0 = blockIdx.x * NBA;
#pragma unroll
  for (int i = 0; i < 8; ++i)
    ((float4*)acc_s)[t + i * 256] = make_float4(0.f, 0.f, 0.f, 0.f);
  __syncthreads();

  int endn = b0 + NBA; if (endn > n) endn = n;
  const int es = row_ptr[b0 << SEG_SHIFT];
  const int ee = row_ptr[endn << SEG_SHIFT];
  const int cnt = ee - es;
  const int s = t >> 5;            // stream 0..7
  const int lane = t & 31;         // float4 lane
  const int chunk = (cnt + 7) >> 3;
  int e = es + s * chunk;
  int eend = e + chunk; if (eend > ee) eend = ee;
  const float4* X4 = (const float4*)x;

  if (e < eend) {
    float4 acc = make_float4(0.f, 0.f, 0.f, 0.f);
    bool first = true;            // first flush may be a shared partial
    int2 rec0 = erec[e];
    int curseg = (rec0.x >> 16) & 63;

#define FLUSH_SEG() do {                                            \
      float* dst_ = &acc_s[curseg * D + lane * 4];                  \
      if (first) {                                                  \
        atomicAdd(dst_ + 0, acc.x); atomicAdd(dst_ + 1, acc.y);     \
        atomicAdd(dst_ + 2, acc.z); atomicAdd(dst_ + 3, acc.w);     \
        first = false;                                              \
      } else {                                                      \
        *(float4*)dst_ = acc;                                       \
      }                                                             \
      acc = make_float4(0.f, 0.f, 0.f, 0.f);                        \
    } while (0)

#define PROC(rec) do {                                              \
      int sg_ = ((rec).x >> 16) & 63;                               \
      if (sg_ != curseg) { FLUSH_SEG(); curseg = sg_; }             \
    } while (0)

    for (; e + 3 < eend; e += 4) {
      int2 r0 = erec[e];
      int2 r1 = erec[e + 1];
      int2 r2 = erec[e + 2];
      int2 r3 = erec[e + 3];
      float4 v0 = X4[(size_t)(r0.x & 0xFFFF) * 32 + lane];
      float4 v1 = X4[(size_t)(r1.x & 0xFFFF) * 32 + lane];
      float4 v2 = X4[(size_t)(r2.x & 0xFFFF) * 32 + lane];
      float4 v3 = X4[(size_t)(r3.x & 0xFFFF) * 32 + lane];
      PROC(r0); fma4(acc, __int_as_float(r0.y), v0);
      PROC(r1); fma4(acc, __int_as_float(r1.y), v1);
      PROC(r2); fma4(acc, __int_as_float(r2.y), v2);
      PROC(r3); fma4(acc, __int_as_float(r3.y), v3);
    }
    for (; e < eend; ++e) {
      int2 r0 = erec[e];
      float4 v0 = X4[(size_t)(r0.x & 0xFFFF) * 32 + lane];
      PROC(r0); fma4(acc, __int_as_float(r0.y), v0);
    }
    // last segment may continue into the next stream -> atomic
    {
      float* dst_ = &acc_s[curseg * D + lane * 4];
      atomicAdd(dst_ + 0, acc.x); atomicAdd(dst_ + 1, acc.y);
      atomicAdd(dst_ + 2, acc.z); atomicAdd(dst_ + 3, acc.w);
    }
#undef PROC
#undef FLUSH_SEG
  }
  __syncthreads();

  // flush: NBA*896 = 7168 bf16 = 3584 uints, 14 per thread
  const int nvalid = endn - b0;
  unsigned int* upd32 = (unsigned int*)upd;
  const size_t ubase = (size_t)b0 * 448;   // *896/2
#pragma unroll
  for (int i = 0; i < 14; ++i) {
    int idx = t + i * 256;        // uint index in tile
    int p = idx * 2;              // elem index
    int node = p / 896;
    int within = p - node * 896;
    int rel = within >> 7, k = within & 127;
    if (node < nvalid) {
      float f0 = acc_s[((node << 3) | rel) * D + k];
      float f1 = acc_s[((node << 3) | rel) * D + k + 1];
      upd32[ubase + idx] = pack_bf2(f0, f1);
    }
  }
}

// ---------- transform GEMM ----------
// h[m,:] = relu( upd(bf16, K=896)@Wrel + x(fp32, K=128)@Wloop + brel + bloop )
__global__ __launch_bounds__(256) void xform_kernel(
    const unsigned short* __restrict__ upd, const float* __restrict__ x,
    const float* __restrict__ Wrel, const float* __restrict__ brel,
    const float* __restrict__ Wloop, const float* __restrict__ bloop,
    float* __restrict__ h, int n) {
  __shared__ float As[TM * 64];    // 16 KB
  const int t = threadIdx.x;
  const int m0 = blockIdx.x * TM;
  const int tc = t & 31, tr = t >> 5;
  const int srow = t >> 2;               // staging row 0..63
  const int sks = (t & 3) * 16;          // staging k-offset
  const int sgrow = m0 + srow;
  float4* As4 = (float4*)As;

  float4 acc[8];
#pragma unroll
  for (int i = 0; i < 8; ++i) acc[i] = make_float4(0.f, 0.f, 0.f, 0.f);

  const float4* Wr4 = (const float4*)Wrel;    // 896 x 32 float4
  for (int kc = 0; kc < RNUM * D; kc += 64) {
    uint4 p0 = make_uint4(0, 0, 0, 0), p1 = p0;
    if (sgrow < n) {
      const uint4* src = (const uint4*)(upd + (size_t)sgrow * 896 + kc + sks);
      p0 = src[0]; p1 = src[1];
    }
    float4 f0, f1, f2, f3;
    f0.x = __uint_as_float(p0.x << 16); f0.y = __uint_as_float(p0.x & 0xFFFF0000u);
    f0.z = __uint_as_float(p0.y << 16); f0.w = __uint_as_float(p0.y & 0xFFFF0000u);
    f1.x = __uint_as_float(p0.z << 16); f1.y = __uint_as_float(p0.z & 0xFFFF0000u);
    f1.z = __uint_as_float(p0.w << 16); f1.w = __uint_as_float(p0.w & 0xFFFF0000u);
    f2.x = __uint_as_float(p1.x << 16); f2.y = __uint_as_float(p1.x & 0xFFFF0000u);
    f2.z = __uint_as_float(p1.y << 16); f2.w = __uint_as_float(p1.y & 0xFFFF0000u);
    f3.x = __uint_as_float(p1.z << 16); f3.y = __uint_as_float(p1.z & 0xFFFF0000u);
    f3.z = __uint_as_float(p1.w << 16); f3.w = __uint_as_float(p1.w & 0xFFFF0000u);
    int sb = (srow * 64 + sks) >> 2;
    As4[sb + 0] = f0; As4[sb + 1] = f1; As4[sb + 2] = f2; As4[sb + 3] = f3;
    __syncthreads();

    for (int k = 0; k < 64; k += 4) {
      float4 a[8];
#pragma unroll
      for (int i = 0; i < 8; ++i)
        a[i] = As4[(tr * 8 + i) * 16 + (k >> 2)];
#pragma unroll
      for (int kk = 0; kk < 4; ++kk) {
        float4 w = Wr4[(size_t)(kc + k + kk) * 32 + tc];
#pragma unroll
        for (int i = 0; i < 8; ++i) {
          float av = (kk == 0) ? a[i].x : (kk == 1) ? a[i].y : (kk == 2) ? a[i].z : a[i].w;
          fma4(acc[i], av, w);
        }
      }
    }
    __syncthreads();
  }

  const float4* X4 = (const float4*)x;
  const float4* Wl4 = (const float4*)Wloop;   // 128 x 32 float4
  for (int kc = 0; kc < D; kc += 64) {
    float4 g0 = make_float4(0, 0, 0, 0), g1 = g0, g2 = g0, g3 = g0;
    if (sgrow < n) {
      const float4* src = &X4[(size_t)sgrow * 32 + ((kc + sks) >> 2)];
      g0 = src[0]; g1 = src[1]; g2 = src[2]; g3 = src[3];
    }
    int sb = (srow * 64 + sks) >> 2;
    As4[sb + 0] = g0; As4[sb + 1] = g1; As4[sb + 2] = g2; As4[sb + 3] = g3;
    __syncthreads();

    for (int k = 0; k < 64; k += 4) {
      float4 a[8];
#pragma unroll
      for (int i = 0; i < 8; ++i)
        a[i] = As4[(tr * 8 + i) * 16 + (k >> 2)];
#pragma unroll
      for (int kk = 0; kk < 4; ++kk) {
        float4 w = Wl4[(size_t)(kc + k + kk) * 32 + tc];
#pragma unroll
        for (int i = 0; i < 8; ++i) {
          float av = (kk == 0) ? a[i].x : (kk == 1) ? a[i].y : (kk == 2) ? a[i].z : a[i].w;
          fma4(acc[i], av, w);
        }
      }
    }
    __syncthreads();
  }

  float4 br = ((const float4*)brel)[tc];
  float4 bl = ((const float4*)bloop)[tc];
  float4 bias = make_float4(br.x + bl.x, br.y + bl.y, br.z + bl.z, br.w + bl.w);
#pragma unroll
  for (int i = 0; i < 8; ++i) {
    int grow = m0 + tr * 8 + i;
    if (grow < n) {
      float4 o;
      o.x = fmaxf(acc[i].x + bias.x, 0.f);
      o.y = fmaxf(acc[i].y + bias.y, 0.f);
      o.z = fmaxf(acc[i].z + bias.z, 0.f);
      o.w = fmaxf(acc[i].w + bias.w, 0.f);
      ((float4*)h)[(size_t)grow * 32 + tc] = o;
    }
  }
}

// ---------- graph pooling (node2graph sorted) ----------
__global__ __launch_bounds__(256) void pool_kernel(const float* __restrict__ x,
    const int* __restrict__ n2g, float* __restrict__ gf, int n) {
  int d = threadIdx.x & 127;
  int sub = threadIdx.x >> 7;
  int n0 = (blockIdx.x * 2 + sub) * 128;
  int nend = n0 + 128;
  if (nend > n) nend = n;
  float acc = 0.f;
  int gcur = -1;
  for (int i = n0; i < nend; ++i) {
    int g = n2g[i];
    if (g != gcur) {
      if (gcur >= 0) atomicAdd(&gf[gcur * D + d], acc);
      gcur = g;
      acc = 0.f;
    }
    acc += x[(size_t)i * D + d];
  }
  if (gcur >= 0) atomicAdd(&gf[gcur * D + d], acc);
}

extern "C" void kernel_launch(void* const* d_in, const int* in_sizes, int n_in,
                              void* d_out, int out_size, void* d_ws, size_t ws_size,
                              hipStream_t stream) {
  const int*   unit_type  = (const int*)d_in[0];
  const int*   node_in    = (const int*)d_in[1];
  const int*   node_out   = (const int*)d_in[2];
  const int*   relation   = (const int*)d_in[3];
  const float* edge_w     = (const float*)d_in[4];
  const int*   node2graph = (const int*)d_in[5];
  const float* emb        = (const float*)d_in[6];
  const float* W_rel      = (const float*)d_in[7];
  const float* b_rel      = (const float*)d_in[8];
  const float* W_loop     = (const float*)d_in[9];
  const float* b_loop     = (const float*)d_in[10];

  const int n  = in_sizes[0];
  const int ne = in_sizes[1];
  float* out = (float*)d_out;

  const int nseg = n << SEG_SHIFT;
  const int nb   = (nseg + 1023) / 1024;

  // workspace layout
  const size_t ND = (size_t)n * D;
  float*          x0       = (float*)d_ws;
  float*          x1       = x0 + ND;
  unsigned short* upd      = (unsigned short*)(x1 + ND);       // N*896 bf16
  int2*           erec     = (int2*)(upd + (size_t)n * RNUM * D);
  int*            hist     = (int*)(erec + ne);
  int*            row_ptr  = hist + nseg;
  int*            cursor   = row_ptr + ((nseg + 4) & ~3);
  int*            partials = cursor + nseg;

  hipMemsetAsync(d_out, 0, (size_t)GNUM * D * sizeof(float), stream);
  hipMemsetAsync(hist, 0, (size_t)nseg * sizeof(int), stream);

  const int eblocks = (ne + 255) / 256;
  hist_kernel<<<eblocks, 256, 0, stream>>>(node_out, relation, hist, ne);
  scan1_kernel<<<nb, 256, 0, stream>>>(hist, row_ptr, partials, nseg);
  scan2_kernel<<<1, 256, 0, stream>>>(partials, nb);
  scan3_kernel<<<(nseg + 255) / 256, 256, 0, stream>>>(row_ptr, cursor, partials, nseg, ne);
  fill_kernel<<<eblocks, 256, 0, stream>>>(node_in, node_out, relation, edge_w,
                                           cursor, erec, ne);

  const int nq = n * 32;
  init_x_kernel<<<(nq + 255) / 256, 256, 0, stream>>>(unit_type, emb, x0, n);

  const int ablocks = (n + NBA - 1) / NBA;
  const int tblocks = (n + TM - 1) / TM;
  float* cur = x0;
  for (int i = 0; i < LAYERS; ++i) {
    float* nxt = (i == LAYERS - 1) ? (out + GNUM * D) : (cur == x0 ? x1 : x0);
    agg_kernel<<<ablocks, 256, 0, stream>>>(cur, erec, row_ptr, upd, n);
    xform_kernel<<<tblocks, 256, 0, stream>>>(
        upd, cur,
        W_rel + (size_t)i * RNUM * D * D, b_rel + (size_t)i * D,
        W_loop + (size_t)i * D * D, b_loop + (size_t)i * D,
        nxt, n);
    cur = nxt;
  }

  pool_kernel<<<(n + 255) / 256, 256, 0, stream>>>(cur, node2graph, out, n);
}

// Round 9
// 1165.015 us; speedup vs baseline: 3.4516x; 1.1731x over previous
//
#include <hip/hip_runtime.h>

#define D 128
#define RNUM 7
#define GNUM 64
#define LAYERS 3
#define NBA 8            // dest nodes per aggregation block
#define SEG_SHIFT 3      // segments = node*8 + rel (slot 7 empty)
#define KTOT 1024        // combined K: 896 (upd) + 128 (x)

typedef __attribute__((ext_vector_type(8))) short bf16x8;
typedef __attribute__((ext_vector_type(4))) float f32x4;

// ---------- x0[n,:] = emb[unit_type[n],:] ----------
__global__ __launch_bounds__(256) void init_x_kernel(const int* __restrict__ ut,
    const float* __restrict__ emb, float* __restrict__ x, int n) {
  int tid = blockIdx.x * 256 + threadIdx.x;
  int nidx = tid >> 5, q = tid & 31;
  if (nidx >= n) return;
  ((float4*)x)[(size_t)nidx * 32 + q] = ((const float4*)emb)[(size_t)ut[nidx] * 32 + q];
}

// ---------- CSR build: histogram over (dest node, rel) segments ----------
__global__ __launch_bounds__(256) void hist_kernel(const int* __restrict__ nout,
    const int* __restrict__ rel, int* __restrict__ hist, int ne) {
  int e = blockIdx.x * 256 + threadIdx.x;
  if (e >= ne) return;
  atomicAdd(&hist[(nout[e] << SEG_SHIFT) | rel[e]], 1);
}

// ---------- scan stage 1 ----------
__global__ __launch_bounds__(256) void scan1_kernel(const int* __restrict__ hist,
    int* __restrict__ row_ptr, int* __restrict__ partials, int nseg) {
  __shared__ int buf[256];
  const int t = threadIdx.x;
  const int base = blockIdx.x * 1024 + t * 4;
  int v0 = 0, v1 = 0, v2 = 0, v3 = 0;
  if (base + 3 < nseg) {
    int4 h4 = *(const int4*)&hist[base];
    v0 = h4.x; v1 = h4.y; v2 = h4.z; v3 = h4.w;
  } else {
    if (base + 0 < nseg) v0 = hist[base + 0];
    if (base + 1 < nseg) v1 = hist[base + 1];
    if (base + 2 < nseg) v2 = hist[base + 2];
    if (base + 3 < nseg) v3 = hist[base + 3];
  }
  int tsum = v0 + v1 + v2 + v3;
  buf[t] = tsum;
  __syncthreads();
  for (int off = 1; off < 256; off <<= 1) {
    int add = (t >= off) ? buf[t - off] : 0;
    __syncthreads();
    buf[t] += add;
    __syncthreads();
  }
  int incl = buf[t];
  int e0 = incl - tsum;
  int e1 = e0 + v0, e2 = e1 + v1, e3 = e2 + v2;
  if (base + 0 < nseg) row_ptr[base + 0] = e0;
  if (base + 1 < nseg) row_ptr[base + 1] = e1;
  if (base + 2 < nseg) row_ptr[base + 2] = e2;
  if (base + 3 < nseg) row_ptr[base + 3] = e3;
  if (t == 255) partials[blockIdx.x] = incl;
}

// ---------- scan stage 2 ----------
__global__ __launch_bounds__(256) void scan2_kernel(int* __restrict__ partials, int nb) {
  __shared__ int buf[256];
  __shared__ int carry_s;
  const int t = threadIdx.x;
  if (t == 0) carry_s = 0;
  __syncthreads();
  for (int c0 = 0; c0 < nb; c0 += 256) {
    int i = c0 + t;
    int v = (i < nb) ? partials[i] : 0;
    buf[t] = v;
    __syncthreads();
    for (int off = 1; off < 256; off <<= 1) {
      int add = (t >= off) ? buf[t - off] : 0;
      __syncthreads();
      buf[t] += add;
      __syncthreads();
    }
    int incl = buf[t];
    int excl = incl - v + carry_s;
    if (i < nb) partials[i] = excl;
    __syncthreads();
    if (t == 255) carry_s += incl;
    __syncthreads();
  }
}

// ---------- scan stage 3 ----------
__global__ __launch_bounds__(256) void scan3_kernel(int* __restrict__ row_ptr,
    int* __restrict__ cursor, const int* __restrict__ partials, int nseg, int ne) {
  int i = blockIdx.x * 256 + threadIdx.x;
  if (i < nseg) {
    int v = row_ptr[i] + partials[i >> 10];
    row_ptr[i] = v;
    cursor[i] = v;
  }
  if (i == 0) row_ptr[nseg] = ne;
}

// ---------- fill: (node_in | rel<<16 | dest_local<<19, ew) ----------
__global__ __launch_bounds__(256) void fill_kernel(const int* __restrict__ nin,
    const int* __restrict__ nout, const int* __restrict__ rel,
    const float* __restrict__ ew, int* __restrict__ cursor,
    int2* __restrict__ erec, int ne) {
  int e = blockIdx.x * 256 + threadIdx.x;
  if (e >= ne) return;
  int r = rel[e];
  int no = nout[e];
  int pos = atomicAdd(&cursor[(no << SEG_SHIFT) | r], 1);
  erec[pos] = make_int2(nin[e] | (r << 16) | ((no & (NBA - 1)) << 19),
                        __float_as_int(ew[e]));
}

__device__ __forceinline__ unsigned int pack_bf2(float a, float b) {
  unsigned int ua = __float_as_uint(a), ub = __float_as_uint(b);
  ua = (ua + 0x7FFFu + ((ua >> 16) & 1u)) >> 16;
  ub = (ub + 0x7FFFu + ((ub >> 16) & 1u)) >> 16;
  return ua | (ub << 16);
}

__device__ __forceinline__ void fma4(float4& d, float s, const float4& v) {
  d.x += s * v.x; d.y += s * v.y; d.z += s * v.z; d.w += s * v.w;
}

// ---------- W prep: Wt[layer][n][k] = bf16([Wrel;Wloop][k][n]) ----------
// layout: [3][128][1024] bf16, k-major within row (pairs packed into uint)
__global__ __launch_bounds__(256) void wt_prep_kernel(
    const float* __restrict__ Wrel, const float* __restrict__ Wloop,
    unsigned int* __restrict__ Wt32) {
  int tid = blockIdx.x * 256 + threadIdx.x;
  if (tid >= LAYERS * 128 * 512) return;
  int layer = tid >> 16;
  int rem = tid & 65535;
  int nrow = rem >> 9;
  int k = (rem & 511) * 2;
  float f0, f1;
  if (k < RNUM * D) {
    const float* base = Wrel + (size_t)layer * RNUM * D * D;
    f0 = base[(size_t)k * D + nrow];
    f1 = base[(size_t)(k + 1) * D + nrow];
  } else {
    const float* base = Wloop + (size_t)layer * D * D;
    f0 = base[(size_t)(k - RNUM * D) * D + nrow];
    f1 = base[(size_t)(k + 1 - RNUM * D) * D + nrow];
  }
  Wt32[tid] = pack_bf2(f0, f1);
}

// ---------- xcvt: updx[m][896..1023] = bf16(x[m][0..127]) ----------
__global__ __launch_bounds__(256) void xcvt_kernel(const float* __restrict__ x,
    unsigned int* __restrict__ updx32, int n) {
  int tid = blockIdx.x * 256 + threadIdx.x;
  int node = tid >> 4, q = tid & 15;
  if (node >= n) return;
  const float4* X4 = (const float4*)x;
  float4 f0 = X4[(size_t)node * 32 + q * 2];
  float4 f1 = X4[(size_t)node * 32 + q * 2 + 1];
  uint4 o;
  o.x = pack_bf2(f0.x, f0.y);
  o.y = pack_bf2(f0.z, f0.w);
  o.z = pack_bf2(f1.x, f1.y);
  o.w = pack_bf2(f1.z, f1.w);
  ((uint4*)&updx32[(size_t)node * 512 + 448])[q] = o;
}

// ---------- edge-parallel aggregation, register segmented-sum ----------
// (round-8 structure; flush now targets 1024-elem updx rows, cols 0..895)
__global__ __launch_bounds__(256) void agg_kernel(
    const float* __restrict__ x, const int2* __restrict__ erec,
    const int* __restrict__ row_ptr, unsigned int* __restrict__ updx32, int n) {
  __shared__ float acc_s[NBA * 8 * D];   // 32 KB
  const int t = threadIdx.x;
  const int b0 = blockIdx.x * NBA;
#pragma unroll
  for (int i = 0; i < 8; ++i)
    ((float4*)acc_s)[t + i * 256] = make_float4(0.f, 0.f, 0.f, 0.f);
  __syncthreads();

  int endn = b0 + NBA; if (endn > n) endn = n;
  const int es = row_ptr[b0 << SEG_SHIFT];
  const int ee = row_ptr[endn << SEG_SHIFT];
  const int cnt = ee - es;
  const int s = t >> 5;            // stream 0..7
  const int lane = t & 31;         // float4 lane
  const int chunk = (cnt + 7) >> 3;
  int e = es + s * chunk;
  int eend = e + chunk; if (eend > ee) eend = ee;
  const float4* X4 = (const float4*)x;

  if (e < eend) {
    float4 acc = make_float4(0.f, 0.f, 0.f, 0.f);
    bool first = true;
    int2 rec0 = erec[e];
    int curseg = (rec0.x >> 16) & 63;

#define FLUSH_SEG() do {                                            \
      float* dst_ = &acc_s[curseg * D + lane * 4];                  \
      if (first) {                                                  \
        atomicAdd(dst_ + 0, acc.x); atomicAdd(dst_ + 1, acc.y);     \
        atomicAdd(dst_ + 2, acc.z); atomicAdd(dst_ + 3, acc.w);     \
        first = false;                                              \
      } else {                                                      \
        *(float4*)dst_ = acc;                                       \
      }                                                             \
      acc = make_float4(0.f, 0.f, 0.f, 0.f);                        \
    } while (0)

#define PROC(rec) do {                                              \
      int sg_ = ((rec).x >> 16) & 63;                               \
      if (sg_ != curseg) { FLUSH_SEG(); curseg = sg_; }             \
    } while (0)

    for (; e + 3 < eend; e += 4) {
      int2 r0 = erec[e];
      int2 r1 = erec[e + 1];
      int2 r2 = erec[e + 2];
      int2 r3 = erec[e + 3];
      float4 v0 = X4[(size_t)(r0.x & 0xFFFF) * 32 + lane];
      float4 v1 = X4[(size_t)(r1.x & 0xFFFF) * 32 + lane];
      float4 v2 = X4[(size_t)(r2.x & 0xFFFF) * 32 + lane];
      float4 v3 = X4[(size_t)(r3.x & 0xFFFF) * 32 + lane];
      PROC(r0); fma4(acc, __int_as_float(r0.y), v0);
      PROC(r1); fma4(acc, __int_as_float(r1.y), v1);
      PROC(r2); fma4(acc, __int_as_float(r2.y), v2);
      PROC(r3); fma4(acc, __int_as_float(r3.y), v3);
    }
    for (; e < eend; ++e) {
      int2 r0 = erec[e];
      float4 v0 = X4[(size_t)(r0.x & 0xFFFF) * 32 + lane];
      PROC(r0); fma4(acc, __int_as_float(r0.y), v0);
    }
    {
      float* dst_ = &acc_s[curseg * D + lane * 4];
      atomicAdd(dst_ + 0, acc.x); atomicAdd(dst_ + 1, acc.y);
      atomicAdd(dst_ + 2, acc.z); atomicAdd(dst_ + 3, acc.w);
    }
#undef PROC
#undef FLUSH_SEG
  }
  __syncthreads();

  // flush tile -> updx rows (stride 512 uints), cols 0..447 (bf16 pairs)
  const int nvalid = endn - b0;
#pragma unroll
  for (int i = 0; i < 14; ++i) {
    int idx = t + i * 256;            // 0..3583 over 8 x 448
    int node = idx / 448;
    int w448 = idx - node * 448;
    int rel = w448 >> 6;              // (w448*2)/128
    int k = (w448 * 2) & 127;
    if (node < nvalid) {
      float f0 = acc_s[((node << 3) | rel) * D + k];
      float f1 = acc_s[((node << 3) | rel) * D + k + 1];
      updx32[(size_t)(b0 + node) * 512 + w448] = pack_bf2(f0, f1);
    }
  }
}

// ---------- MFMA transform ----------
// h = relu( updx(N x 1024 bf16) @ Wt^T + brel + bloop )
// Block: 64 rows, 4 waves; wave w -> rows [m0+w*16, +16), 8 col-tiles of
// mfma_f32_16x16x32_bf16. A/B frags are direct 16B global loads (B from
// transposed Wt, L2-resident). No LDS.
__global__ __launch_bounds__(256) void xform_kernel(
    const unsigned short* __restrict__ updx, const unsigned short* __restrict__ Wt,
    const float* __restrict__ brel, const float* __restrict__ bloop,
    float* __restrict__ h, int n) {
  const int t = threadIdx.x;
  const int w = t >> 6, lane = t & 63;
  const int m0 = blockIdx.x * 64 + w * 16;
  const int rt = lane & 15, quad = lane >> 4;

  const unsigned short* a_ptr = updx + (size_t)(m0 + rt) * KTOT + quad * 8;
  const unsigned short* b_ptr = Wt + (size_t)rt * KTOT + quad * 8;

  f32x4 acc[8];
#pragma unroll
  for (int c = 0; c < 8; ++c) acc[c] = (f32x4){0.f, 0.f, 0.f, 0.f};

  for (int kc = 0; kc < KTOT; kc += 32) {
    bf16x8 af = *(const bf16x8*)(a_ptr + kc);
#pragma unroll
    for (int c = 0; c < 8; ++c) {
      bf16x8 bf = *(const bf16x8*)(b_ptr + (size_t)c * 16 * KTOT + kc);
      acc[c] = __builtin_amdgcn_mfma_f32_16x16x32_bf16(af, bf, acc[c], 0, 0, 0);
    }
  }

  // C/D layout: col = lane&15 (rt), row = quad*4 + reg
#pragma unroll
  for (int c = 0; c < 8; ++c) {
    int col = c * 16 + rt;
    float bias = brel[col] + bloop[col];
#pragma unroll
    for (int r = 0; r < 4; ++r) {
      int m = m0 + quad * 4 + r;
      if (m < n) h[(size_t)m * D + col] = fmaxf(acc[c][r] + bias, 0.f);
    }
  }
}

// ---------- graph pooling (node2graph sorted) ----------
__global__ __launch_bounds__(256) void pool_kernel(const float* __restrict__ x,
    const int* __restrict__ n2g, float* __restrict__ gf, int n) {
  int d = threadIdx.x & 127;
  int sub = threadIdx.x >> 7;
  int n0 = (blockIdx.x * 2 + sub) * 128;
  int nend = n0 + 128;
  if (nend > n) nend = n;
  float acc = 0.f;
  int gcur = -1;
  for (int i = n0; i < nend; ++i) {
    int g = n2g[i];
    if (g != gcur) {
      if (gcur >= 0) atomicAdd(&gf[gcur * D + d], acc);
      gcur = g;
      acc = 0.f;
    }
    acc += x[(size_t)i * D + d];
  }
  if (gcur >= 0) atomicAdd(&gf[gcur * D + d], acc);
}

extern "C" void kernel_launch(void* const* d_in, const int* in_sizes, int n_in,
                              void* d_out, int out_size, void* d_ws, size_t ws_size,
                              hipStream_t stream) {
  const int*   unit_type  = (const int*)d_in[0];
  const int*   node_in    = (const int*)d_in[1];
  const int*   node_out   = (const int*)d_in[2];
  const int*   relation   = (const int*)d_in[3];
  const float* edge_w     = (const float*)d_in[4];
  const int*   node2graph = (const int*)d_in[5];
  const float* emb        = (const float*)d_in[6];
  const float* W_rel      = (const float*)d_in[7];
  const float* b_rel      = (const float*)d_in[8];
  const float* W_loop     = (const float*)d_in[9];
  const float* b_loop     = (const float*)d_in[10];

  const int n  = in_sizes[0];
  const int ne = in_sizes[1];
  float* out = (float*)d_out;

  const int nseg = n << SEG_SHIFT;
  const int nb   = (nseg + 1023) / 1024;

  // workspace layout
  const size_t ND = (size_t)n * D;
  float*          x0       = (float*)d_ws;
  float*          x1       = x0 + ND;
  unsigned short* updx     = (unsigned short*)(x1 + ND);          // N x 1024 bf16
  unsigned short* Wt       = updx + (size_t)n * KTOT;             // 3 x 128 x 1024 bf16
  int2*           erec     = (int2*)(Wt + (size_t)LAYERS * D * KTOT);
  int*            hist     = (int*)(erec + ne);
  int*            row_ptr  = hist + nseg;
  int*            cursor   = row_ptr + ((nseg + 4) & ~3);
  int*            partials = cursor + nseg;

  hipMemsetAsync(d_out, 0, (size_t)GNUM * D * sizeof(float), stream);
  hipMemsetAsync(hist, 0, (size_t)nseg * sizeof(int), stream);

  const int eblocks = (ne + 255) / 256;
  hist_kernel<<<eblocks, 256, 0, stream>>>(node_out, relation, hist, ne);
  scan1_kernel<<<nb, 256, 0, stream>>>(hist, row_ptr, partials, nseg);
  scan2_kernel<<<1, 256, 0, stream>>>(partials, nb);
  scan3_kernel<<<(nseg + 255) / 256, 256, 0, stream>>>(row_ptr, cursor, partials, nseg, ne);
  fill_kernel<<<eblocks, 256, 0, stream>>>(node_in, node_out, relation, edge_w,
                                           cursor, erec, ne);

  wt_prep_kernel<<<(LAYERS * 128 * 512 + 255) / 256, 256, 0, stream>>>(
      W_rel, W_loop, (unsigned int*)Wt);

  const int nq = n * 32;
  init_x_kernel<<<(nq + 255) / 256, 256, 0, stream>>>(unit_type, emb, x0, n);

  const int ablocks = (n + NBA - 1) / NBA;
  const int cblocks = (n * 16 + 255) / 256;
  const int tblocks = (n + 63) / 64;
  float* cur = x0;
  for (int i = 0; i < LAYERS; ++i) {
    float* nxt = (i == LAYERS - 1) ? (out + GNUM * D) : (cur == x0 ? x1 : x0);
    agg_kernel<<<ablocks, 256, 0, stream>>>(cur, erec, row_ptr,
                                            (unsigned int*)updx, n);
    xcvt_kernel<<<cblocks, 256, 0, stream>>>(cur, (unsigned int*)updx, n);
    xform_kernel<<<tblocks, 256, 0, stream>>>(
        updx, Wt + (size_t)i * D * KTOT,
        b_rel + (size_t)i * D, b_loop + (size_t)i * D, nxt, n);
    cur = nxt;
  }

  pool_kernel<<<(n + 255) / 256, 256, 0, stream>>>(cur, node2graph, out, n);
}

// Round 10
// 1033.082 us; speedup vs baseline: 3.8924x; 1.1277x over previous
//
#include <hip/hip_runtime.h>

#define D 128
#define RNUM 7
#define GNUM 64
#define LAYERS 3
#define NBA 8            // dest nodes per aggregation block
#define SEG_SHIFT 3      // segments = node*8 + rel (slot 7 empty)
#define KTOT 1024        // combined K: 896 (upd) + 128 (x)

typedef __attribute__((ext_vector_type(8))) short bf16x8;
typedef __attribute__((ext_vector_type(4))) float f32x4;

// ---------- CSR build: histogram over (dest node, rel) segments ----------
__global__ __launch_bounds__(256) void hist_kernel(const int* __restrict__ nout,
    const int* __restrict__ rel, int* __restrict__ hist, int ne) {
  int e = blockIdx.x * 256 + threadIdx.x;
  if (e >= ne) return;
  atomicAdd(&hist[(nout[e] << SEG_SHIFT) | rel[e]], 1);
}

// ---------- scan stage 1 ----------
__global__ __launch_bounds__(256) void scan1_kernel(const int* __restrict__ hist,
    int* __restrict__ row_ptr, int* __restrict__ partials, int nseg) {
  __shared__ int buf[256];
  const int t = threadIdx.x;
  const int base = blockIdx.x * 1024 + t * 4;
  int v0 = 0, v1 = 0, v2 = 0, v3 = 0;
  if (base + 3 < nseg) {
    int4 h4 = *(const int4*)&hist[base];
    v0 = h4.x; v1 = h4.y; v2 = h4.z; v3 = h4.w;
  } else {
    if (base + 0 < nseg) v0 = hist[base + 0];
    if (base + 1 < nseg) v1 = hist[base + 1];
    if (base + 2 < nseg) v2 = hist[base + 2];
    if (base + 3 < nseg) v3 = hist[base + 3];
  }
  int tsum = v0 + v1 + v2 + v3;
  buf[t] = tsum;
  __syncthreads();
  for (int off = 1; off < 256; off <<= 1) {
    int add = (t >= off) ? buf[t - off] : 0;
    __syncthreads();
    buf[t] += add;
    __syncthreads();
  }
  int incl = buf[t];
  int e0 = incl - tsum;
  int e1 = e0 + v0, e2 = e1 + v1, e3 = e2 + v2;
  if (base + 0 < nseg) row_ptr[base + 0] = e0;
  if (base + 1 < nseg) row_ptr[base + 1] = e1;
  if (base + 2 < nseg) row_ptr[base + 2] = e2;
  if (base + 3 < nseg) row_ptr[base + 3] = e3;
  if (t == 255) partials[blockIdx.x] = incl;
}

// ---------- scan stage 2 ----------
__global__ __launch_bounds__(256) void scan2_kernel(int* __restrict__ partials, int nb) {
  __shared__ int buf[256];
  __shared__ int carry_s;
  const int t = threadIdx.x;
  if (t == 0) carry_s = 0;
  __syncthreads();
  for (int c0 = 0; c0 < nb; c0 += 256) {
    int i = c0 + t;
    int v = (i < nb) ? partials[i] : 0;
    buf[t] = v;
    __syncthreads();
    for (int off = 1; off < 256; off <<= 1) {
      int add = (t >= off) ? buf[t - off] : 0;
      __syncthreads();
      buf[t] += add;
      __syncthreads();
    }
    int incl = buf[t];
    int excl = incl - v + carry_s;
    if (i < nb) partials[i] = excl;
    __syncthreads();
    if (t == 255) carry_s += incl;
    __syncthreads();
  }
}

// ---------- scan stage 3 ----------
__global__ __launch_bounds__(256) void scan3_kernel(int* __restrict__ row_ptr,
    int* __restrict__ cursor, const int* __restrict__ partials, int nseg, int ne) {
  int i = blockIdx.x * 256 + threadIdx.x;
  if (i < nseg) {
    int v = row_ptr[i] + partials[i >> 10];
    row_ptr[i] = v;
    cursor[i] = v;
  }
  if (i == 0) row_ptr[nseg] = ne;
}

// ---------- fill: (node_in | rel<<16 | dest_local<<19, ew) ----------
__global__ __launch_bounds__(256) void fill_kernel(const int* __restrict__ nin,
    const int* __restrict__ nout, const int* __restrict__ rel,
    const float* __restrict__ ew, int* __restrict__ cursor,
    int2* __restrict__ erec, int ne) {
  int e = blockIdx.x * 256 + threadIdx.x;
  if (e >= ne) return;
  int r = rel[e];
  int no = nout[e];
  int pos = atomicAdd(&cursor[(no << SEG_SHIFT) | r], 1);
  erec[pos] = make_int2(nin[e] | (r << 16) | ((no & (NBA - 1)) << 19),
                        __float_as_int(ew[e]));
}

__device__ __forceinline__ unsigned int pack_bf2(float a, float b) {
  unsigned int ua = __float_as_uint(a), ub = __float_as_uint(b);
  ua = (ua + 0x7FFFu + ((ua >> 16) & 1u)) >> 16;
  ub = (ub + 0x7FFFu + ((ub >> 16) & 1u)) >> 16;
  return ua | (ub << 16);
}

__device__ __forceinline__ unsigned short bf1(float a) {
  unsigned int u = __float_as_uint(a);
  u = (u + 0x7FFFu + ((u >> 16) & 1u)) >> 16;
  return (unsigned short)u;
}

__device__ __forceinline__ float4 bf4_to_f4(uint2 p) {
  float4 f;
  f.x = __uint_as_float(p.x << 16);
  f.y = __uint_as_float(p.x & 0xFFFF0000u);
  f.z = __uint_as_float(p.y << 16);
  f.w = __uint_as_float(p.y & 0xFFFF0000u);
  return f;
}

__device__ __forceinline__ void fma4(float4& d, float s, const float4& v) {
  d.x += s * v.x; d.y += s * v.y; d.z += s * v.z; d.w += s * v.w;
}

// ---------- W prep: Wt[layer][n][k] = bf16([Wrel;Wloop][k][n]) ----------
__global__ __launch_bounds__(256) void wt_prep_kernel(
    const float* __restrict__ Wrel, const float* __restrict__ Wloop,
    unsigned int* __restrict__ Wt32) {
  int tid = blockIdx.x * 256 + threadIdx.x;
  if (tid >= LAYERS * 128 * 512) return;
  int layer = tid >> 16;
  int rem = tid & 65535;
  int nrow = rem >> 9;
  int k = (rem & 511) * 2;
  float f0, f1;
  if (k < RNUM * D) {
    const float* base = Wrel + (size_t)layer * RNUM * D * D;
    f0 = base[(size_t)k * D + nrow];
    f1 = base[(size_t)(k + 1) * D + nrow];
  } else {
    const float* base = Wloop + (size_t)layer * D * D;
    f0 = base[(size_t)(k - RNUM * D) * D + nrow];
    f1 = base[(size_t)(k + 1 - RNUM * D) * D + nrow];
  }
  Wt32[tid] = pack_bf2(f0, f1);
}

// ---------- init: updx[m][896..1023] = bf16(emb[ut[m]][:]) ----------
__global__ __launch_bounds__(256) void initx_kernel(const int* __restrict__ ut,
    const float* __restrict__ emb, unsigned int* __restrict__ updx32, int n) {
  int tid = blockIdx.x * 256 + threadIdx.x;
  int node = tid >> 4, q = tid & 15;
  if (node >= n) return;
  const float4* E4 = (const float4*)emb;
  int u = ut[node];
  float4 f0 = E4[(size_t)u * 32 + q * 2];
  float4 f1 = E4[(size_t)u * 32 + q * 2 + 1];
  uint4 o;
  o.x = pack_bf2(f0.x, f0.y);
  o.y = pack_bf2(f0.z, f0.w);
  o.z = pack_bf2(f1.x, f1.y);
  o.w = pack_bf2(f1.z, f1.w);
  ((uint4*)&updx32[(size_t)node * 512 + 448])[q] = o;
}

// ---------- edge-parallel aggregation, register segmented-sum ----------
// Gathers bf16 x rows (256 B) from updx's x-section; fp32 accumulate.
__global__ __launch_bounds__(256) void agg_kernel(
    const int2* __restrict__ erec, const int* __restrict__ row_ptr,
    unsigned int* __restrict__ updx32, int n) {
  __shared__ float acc_s[NBA * 8 * D];   // 32 KB
  const int t = threadIdx.x;
  const int b0 = blockIdx.x * NBA;
#pragma unroll
  for (int i = 0; i < 8; ++i)
    ((float4*)acc_s)[t + i * 256] = make_float4(0.f, 0.f, 0.f, 0.f);
  __syncthreads();

  int endn = b0 + NBA; if (endn > n) endn = n;
  const int es = row_ptr[b0 << SEG_SHIFT];
  const int ee = row_ptr[endn << SEG_SHIFT];
  const int cnt = ee - es;
  const int s = t >> 5;            // stream 0..7
  const int lane = t & 31;         // 4-elem lane within 128-float row
  const int chunk = (cnt + 7) >> 3;
  int e = es + s * chunk;
  int eend = e + chunk; if (eend > ee) eend = ee;
  // x-section: row j at updx32[j*512 + 448], lane reads uint2 at +lane*2
  const unsigned int* XB = updx32 + 448 + lane * 2;

  if (e < eend) {
    float4 acc = make_float4(0.f, 0.f, 0.f, 0.f);
    bool first = true;
    int2 rec0 = erec[e];
    int curseg = (rec0.x >> 16) & 63;

#define FLUSH_SEG() do {                                            \
      float* dst_ = &acc_s[curseg * D + lane * 4];                  \
      if (first) {                                                  \
        atomicAdd(dst_ + 0, acc.x); atomicAdd(dst_ + 1, acc.y);     \
        atomicAdd(dst_ + 2, acc.z); atomicAdd(dst_ + 3, acc.w);     \
        first = false;                                              \
      } else {                                                      \
        *(float4*)dst_ = acc;                                       \
      }                                                             \
      acc = make_float4(0.f, 0.f, 0.f, 0.f);                        \
    } while (0)

#define PROC(rec) do {                                              \
      int sg_ = ((rec).x >> 16) & 63;                               \
      if (sg_ != curseg) { FLUSH_SEG(); curseg = sg_; }             \
    } while (0)

    for (; e + 3 < eend; e += 4) {
      int2 r0 = erec[e];
      int2 r1 = erec[e + 1];
      int2 r2 = erec[e + 2];
      int2 r3 = erec[e + 3];
      uint2 p0 = *(const uint2*)(XB + (size_t)(r0.x & 0xFFFF) * 512);
      uint2 p1 = *(const uint2*)(XB + (size_t)(r1.x & 0xFFFF) * 512);
      uint2 p2 = *(const uint2*)(XB + (size_t)(r2.x & 0xFFFF) * 512);
      uint2 p3 = *(const uint2*)(XB + (size_t)(r3.x & 0xFFFF) * 512);
      PROC(r0); fma4(acc, __int_as_float(r0.y), bf4_to_f4(p0));
      PROC(r1); fma4(acc, __int_as_float(r1.y), bf4_to_f4(p1));
      PROC(r2); fma4(acc, __int_as_float(r2.y), bf4_to_f4(p2));
      PROC(r3); fma4(acc, __int_as_float(r3.y), bf4_to_f4(p3));
    }
    for (; e < eend; ++e) {
      int2 r0 = erec[e];
      uint2 p0 = *(const uint2*)(XB + (size_t)(r0.x & 0xFFFF) * 512);
      PROC(r0); fma4(acc, __int_as_float(r0.y), bf4_to_f4(p0));
    }
    {
      float* dst_ = &acc_s[curseg * D + lane * 4];
      atomicAdd(dst_ + 0, acc.x); atomicAdd(dst_ + 1, acc.y);
      atomicAdd(dst_ + 2, acc.z); atomicAdd(dst_ + 3, acc.w);
    }
#undef PROC
#undef FLUSH_SEG
  }
  __syncthreads();

  // flush tile -> updx rows (stride 512 uints), cols 0..447 (bf16 pairs)
  const int nvalid = endn - b0;
#pragma unroll
  for (int i = 0; i < 14; ++i) {
    int idx = t + i * 256;            // 0..3583 over 8 x 448
    int node = idx / 448;
    int w448 = idx - node * 448;
    int rel = w448 >> 6;
    int k = (w448 * 2) & 127;
    if (node < nvalid) {
      float f0 = acc_s[((node << 3) | rel) * D + k];
      float f1 = acc_s[((node << 3) | rel) * D + k + 1];
      updx32[(size_t)(b0 + node) * 512 + w448] = pack_bf2(f0, f1);
    }
  }
}

// ---------- MFMA transform ----------
// h = relu( updx(N x 1024 bf16) @ Wt^T + biases ).
// Intermediate layers: write bf16 h into updx x-section (cols 896..1023).
// Final layer: write fp32 h to hout. Wave reads its own rows' K before its
// epilogue overwrites the x-section, so in-place is safe.
__global__ __launch_bounds__(256) void xform_kernel(
    unsigned short* __restrict__ updx, const unsigned short* __restrict__ Wt,
    const float* __restrict__ brel, const float* __restrict__ bloop,
    float* __restrict__ hout, int n, int write_fp32) {
  const int t = threadIdx.x;
  const int w = t >> 6, lane = t & 63;
  const int m0 = blockIdx.x * 64 + w * 16;
  const int rt = lane & 15, quad = lane >> 4;

  const unsigned short* a_ptr = updx + (size_t)(m0 + rt) * KTOT + quad * 8;
  const unsigned short* b_ptr = Wt + (size_t)rt * KTOT + quad * 8;

  f32x4 acc[8];
#pragma unroll
  for (int c = 0; c < 8; ++c) acc[c] = (f32x4){0.f, 0.f, 0.f, 0.f};

  for (int kc = 0; kc < KTOT; kc += 32) {
    bf16x8 af = *(const bf16x8*)(a_ptr + kc);
#pragma unroll
    for (int c = 0; c < 8; ++c) {
      bf16x8 bf = *(const bf16x8*)(b_ptr + (size_t)c * 16 * KTOT + kc);
      acc[c] = __builtin_amdgcn_mfma_f32_16x16x32_bf16(af, bf, acc[c], 0, 0, 0);
    }
  }

  // C/D layout: col = lane&15 (rt), row = quad*4 + reg
#pragma unroll
  for (int c = 0; c < 8; ++c) {
    int col = c * 16 + rt;
    float bias = brel[col] + bloop[col];
#pragma unroll
    for (int r = 0; r < 4; ++r) {
      int m = m0 + quad * 4 + r;
      if (m < n) {
        float v = fmaxf(acc[c][r] + bias, 0.f);
        if (write_fp32) hout[(size_t)m * D + col] = v;
        else updx[(size_t)m * KTOT + 896 + col] = bf1(v);
      }
    }
  }
}

// ---------- graph pooling (node2graph sorted) ----------
__global__ __launch_bounds__(256) void pool_kernel(const float* __restrict__ x,
    const int* __restrict__ n2g, float* __restrict__ gf, int n) {
  int d = threadIdx.x & 127;
  int sub = threadIdx.x >> 7;
  int n0 = (blockIdx.x * 2 + sub) * 128;
  int nend = n0 + 128;
  if (nend > n) nend = n;
  float acc = 0.f;
  int gcur = -1;
  for (int i = n0; i < nend; ++i) {
    int g = n2g[i];
    if (g != gcur) {
      if (gcur >= 0) atomicAdd(&gf[gcur * D + d], acc);
      gcur = g;
      acc = 0.f;
    }
    acc += x[(size_t)i * D + d];
  }
  if (gcur >= 0) atomicAdd(&gf[gcur * D + d], acc);
}

extern "C" void kernel_launch(void* const* d_in, const int* in_sizes, int n_in,
                              void* d_out, int out_size, void* d_ws, size_t ws_size,
                              hipStream_t stream) {
  const int*   unit_type  = (const int*)d_in[0];
  const int*   node_in    = (const int*)d_in[1];
  const int*   node_out   = (const int*)d_in[2];
  const int*   relation   = (const int*)d_in[3];
  const float* edge_w     = (const float*)d_in[4];
  const int*   node2graph = (const int*)d_in[5];
  const float* emb        = (const float*)d_in[6];
  const float* W_rel      = (const float*)d_in[7];
  const float* b_rel      = (const float*)d_in[8];
  const float* W_loop     = (const float*)d_in[9];
  const float* b_loop     = (const float*)d_in[10];

  const int n  = in_sizes[0];
  const int ne = in_sizes[1];
  float* out = (float*)d_out;

  const int nseg = n << SEG_SHIFT;
  const int nb   = (nseg + 1023) / 1024;

  // workspace layout
  unsigned short* updx     = (unsigned short*)d_ws;               // N x 1024 bf16
  unsigned short* Wt       = updx + (size_t)n * KTOT;             // 3 x 128 x 1024 bf16
  int2*           erec     = (int2*)(Wt + (size_t)LAYERS * D * KTOT);
  int*            hist     = (int*)(erec + ne);
  int*            row_ptr  = hist + nseg;
  int*            cursor   = row_ptr + ((nseg + 4) & ~3);
  int*            partials = cursor + nseg;

  hipMemsetAsync(d_out, 0, (size_t)GNUM * D * sizeof(float), stream);
  hipMemsetAsync(hist, 0, (size_t)nseg * sizeof(int), stream);

  const int eblocks = (ne + 255) / 256;
  hist_kernel<<<eblocks, 256, 0, stream>>>(node_out, relation, hist, ne);
  scan1_kernel<<<nb, 256, 0, stream>>>(hist, row_ptr, partials, nseg);
  scan2_kernel<<<1, 256, 0, stream>>>(partials, nb);
  scan3_kernel<<<(nseg + 255) / 256, 256, 0, stream>>>(row_ptr, cursor, partials, nseg, ne);
  fill_kernel<<<eblocks, 256, 0, stream>>>(node_in, node_out, relation, edge_w,
                                           cursor, erec, ne);

  wt_prep_kernel<<<(LAYERS * 128 * 512 + 255) / 256, 256, 0, stream>>>(
      W_rel, W_loop, (unsigned int*)Wt);

  initx_kernel<<<(n * 16 + 255) / 256, 256, 0, stream>>>(
      unit_type, emb, (unsigned int*)updx, n);

  const int ablocks = (n + NBA - 1) / NBA;
  const int tblocks = (n + 63) / 64;
  float* xfinal = out + GNUM * D;
  for (int i = 0; i < LAYERS; ++i) {
    agg_kernel<<<ablocks, 256, 0, stream>>>(erec, row_ptr,
                                            (unsigned int*)updx, n);
    xform_kernel<<<tblocks, 256, 0, stream>>>(
        updx, Wt + (size_t)i * D * KTOT,
        b_rel + (size_t)i * D, b_loop + (size_t)i * D,
        xfinal, n, (i == LAYERS - 1) ? 1 : 0);
  }

  pool_kernel<<<(n + 255) / 256, 256, 0, stream>>>(xfinal, node2graph, out, n);
}

// Round 11
// 915.803 us; speedup vs baseline: 4.3908x; 1.1281x over previous
//
#include <hip/hip_runtime.h>

#define D 128
#define RNUM 7
#define GNUM 64
#define LAYERS 3
#define NBA 8            // dest nodes per aggregation block
#define SEG_SHIFT 3      // segments = node*8 + rel (slot 7 empty)
#define KTOT 1024        // combined K: 896 (upd) + 128 (x)

typedef __attribute__((ext_vector_type(8))) short bf16x8;
typedef __attribute__((ext_vector_type(4))) float f32x4;

// ---------- CSR build: histogram over (dest node, rel) segments ----------
__global__ __launch_bounds__(256) void hist_kernel(const int* __restrict__ nout,
    const int* __restrict__ rel, int* __restrict__ hist, int ne) {
  int e = blockIdx.x * 256 + threadIdx.x;
  if (e >= ne) return;
  atomicAdd(&hist[(nout[e] << SEG_SHIFT) | rel[e]], 1);
}

// ---------- scan stage 1 ----------
__global__ __launch_bounds__(256) void scan1_kernel(const int* __restrict__ hist,
    int* __restrict__ row_ptr, int* __restrict__ partials, int nseg) {
  __shared__ int buf[256];
  const int t = threadIdx.x;
  const int base = blockIdx.x * 1024 + t * 4;
  int v0 = 0, v1 = 0, v2 = 0, v3 = 0;
  if (base + 3 < nseg) {
    int4 h4 = *(const int4*)&hist[base];
    v0 = h4.x; v1 = h4.y; v2 = h4.z; v3 = h4.w;
  } else {
    if (base + 0 < nseg) v0 = hist[base + 0];
    if (base + 1 < nseg) v1 = hist[base + 1];
    if (base + 2 < nseg) v2 = hist[base + 2];
    if (base + 3 < nseg) v3 = hist[base + 3];
  }
  int tsum = v0 + v1 + v2 + v3;
  buf[t] = tsum;
  __syncthreads();
  for (int off = 1; off < 256; off <<= 1) {
    int add = (t >= off) ? buf[t - off] : 0;
    __syncthreads();
    buf[t] += add;
    __syncthreads();
  }
  int incl = buf[t];
  int e0 = incl - tsum;
  int e1 = e0 + v0, e2 = e1 + v1, e3 = e2 + v2;
  if (base + 0 < nseg) row_ptr[base + 0] = e0;
  if (base + 1 < nseg) row_ptr[base + 1] = e1;
  if (base + 2 < nseg) row_ptr[base + 2] = e2;
  if (base + 3 < nseg) row_ptr[base + 3] = e3;
  if (t == 255) partials[blockIdx.x] = incl;
}

// ---------- scan stage 2 ----------
__global__ __launch_bounds__(256) void scan2_kernel(int* __restrict__ partials, int nb) {
  __shared__ int buf[256];
  __shared__ int carry_s;
  const int t = threadIdx.x;
  if (t == 0) carry_s = 0;
  __syncthreads();
  for (int c0 = 0; c0 < nb; c0 += 256) {
    int i = c0 + t;
    int v = (i < nb) ? partials[i] : 0;
    buf[t] = v;
    __syncthreads();
    for (int off = 1; off < 256; off <<= 1) {
      int add = (t >= off) ? buf[t - off] : 0;
      __syncthreads();
      buf[t] += add;
      __syncthreads();
    }
    int incl = buf[t];
    int excl = incl - v + carry_s;
    if (i < nb) partials[i] = excl;
    __syncthreads();
    if (t == 255) carry_s += incl;
    __syncthreads();
  }
}

// ---------- scan stage 3 ----------
__global__ __launch_bounds__(256) void scan3_kernel(int* __restrict__ row_ptr,
    int* __restrict__ cursor, const int* __restrict__ partials, int nseg, int ne) {
  int i = blockIdx.x * 256 + threadIdx.x;
  if (i < nseg) {
    int v = row_ptr[i] + partials[i >> 10];
    row_ptr[i] = v;
    cursor[i] = v;
  }
  if (i == 0) row_ptr[nseg] = ne;
}

// ---------- fill: (node_in | rel<<16 | dest_local<<19, ew) ----------
__global__ __launch_bounds__(256) void fill_kernel(const int* __restrict__ nin,
    const int* __restrict__ nout, const int* __restrict__ rel,
    const float* __restrict__ ew, int* __restrict__ cursor,
    int2* __restrict__ erec, int ne) {
  int e = blockIdx.x * 256 + threadIdx.x;
  if (e >= ne) return;
  int r = rel[e];
  int no = nout[e];
  int pos = atomicAdd(&cursor[(no << SEG_SHIFT) | r], 1);
  erec[pos] = make_int2(nin[e] | (r << 16) | ((no & (NBA - 1)) << 19),
                        __float_as_int(ew[e]));
}

__device__ __forceinline__ unsigned int pack_bf2(float a, float b) {
  unsigned int ua = __float_as_uint(a), ub = __float_as_uint(b);
  ua = (ua + 0x7FFFu + ((ua >> 16) & 1u)) >> 16;
  ub = (ub + 0x7FFFu + ((ub >> 16) & 1u)) >> 16;
  return ua | (ub << 16);
}

__device__ __forceinline__ unsigned short bf1(float a) {
  unsigned int u = __float_as_uint(a);
  u = (u + 0x7FFFu + ((u >> 16) & 1u)) >> 16;
  return (unsigned short)u;
}

__device__ __forceinline__ float4 bf4_to_f4(uint2 p) {
  float4 f;
  f.x = __uint_as_float(p.x << 16);
  f.y = __uint_as_float(p.x & 0xFFFF0000u);
  f.z = __uint_as_float(p.y << 16);
  f.w = __uint_as_float(p.y & 0xFFFF0000u);
  return f;
}

__device__ __forceinline__ void fma4(float4& d, float s, const float4& v) {
  d.x += s * v.x; d.y += s * v.y; d.z += s * v.z; d.w += s * v.w;
}

// ---------- W prep: Wt[layer][n][k] = bf16([Wrel;Wloop][k][n]) ----------
__global__ __launch_bounds__(256) void wt_prep_kernel(
    const float* __restrict__ Wrel, const float* __restrict__ Wloop,
    unsigned int* __restrict__ Wt32) {
  int tid = blockIdx.x * 256 + threadIdx.x;
  if (tid >= LAYERS * 128 * 512) return;
  int layer = tid >> 16;
  int rem = tid & 65535;
  int nrow = rem >> 9;
  int k = (rem & 511) * 2;
  float f0, f1;
  if (k < RNUM * D) {
    const float* base = Wrel + (size_t)layer * RNUM * D * D;
    f0 = base[(size_t)k * D + nrow];
    f1 = base[(size_t)(k + 1) * D + nrow];
  } else {
    const float* base = Wloop + (size_t)layer * D * D;
    f0 = base[(size_t)(k - RNUM * D) * D + nrow];
    f1 = base[(size_t)(k + 1 - RNUM * D) * D + nrow];
  }
  Wt32[tid] = pack_bf2(f0, f1);
}

// ---------- init: updx[m][896..1023] = bf16(emb[ut[m]][:]) ----------
__global__ __launch_bounds__(256) void initx_kernel(const int* __restrict__ ut,
    const float* __restrict__ emb, unsigned int* __restrict__ updx32, int n) {
  int tid = blockIdx.x * 256 + threadIdx.x;
  int node = tid >> 4, q = tid & 15;
  if (node >= n) return;
  const float4* E4 = (const float4*)emb;
  int u = ut[node];
  float4 f0 = E4[(size_t)u * 32 + q * 2];
  float4 f1 = E4[(size_t)u * 32 + q * 2 + 1];
  uint4 o;
  o.x = pack_bf2(f0.x, f0.y);
  o.y = pack_bf2(f0.z, f0.w);
  o.z = pack_bf2(f1.x, f1.y);
  o.w = pack_bf2(f1.z, f1.w);
  ((uint4*)&updx32[(size_t)node * 512 + 448])[q] = o;
}

// ---------- edge-parallel aggregation, register segmented-sum ----------
__global__ __launch_bounds__(256) void agg_kernel(
    const int2* __restrict__ erec, const int* __restrict__ row_ptr,
    unsigned int* __restrict__ updx32, int n) {
  __shared__ float acc_s[NBA * 8 * D];   // 32 KB
  const int t = threadIdx.x;
  const int b0 = blockIdx.x * NBA;
#pragma unroll
  for (int i = 0; i < 8; ++i)
    ((float4*)acc_s)[t + i * 256] = make_float4(0.f, 0.f, 0.f, 0.f);
  __syncthreads();

  int endn = b0 + NBA; if (endn > n) endn = n;
  const int es = row_ptr[b0 << SEG_SHIFT];
  const int ee = row_ptr[endn << SEG_SHIFT];
  const int cnt = ee - es;
  const int s = t >> 5;            // stream 0..7
  const int lane = t & 31;         // 4-elem lane within 128-float row
  const int chunk = (cnt + 7) >> 3;
  int e = es + s * chunk;
  int eend = e + chunk; if (eend > ee) eend = ee;
  const unsigned int* XB = updx32 + 448 + lane * 2;

  if (e < eend) {
    float4 acc = make_float4(0.f, 0.f, 0.f, 0.f);
    bool first = true;
    int2 rec0 = erec[e];
    int curseg = (rec0.x >> 16) & 63;

#define FLUSH_SEG() do {                                            \
      float* dst_ = &acc_s[curseg * D + lane * 4];                  \
      if (first) {                                                  \
        atomicAdd(dst_ + 0, acc.x); atomicAdd(dst_ + 1, acc.y);     \
        atomicAdd(dst_ + 2, acc.z); atomicAdd(dst_ + 3, acc.w);     \
        first = false;                                              \
      } else {                                                      \
        *(float4*)dst_ = acc;                                       \
      }                                                             \
      acc = make_float4(0.f, 0.f, 0.f, 0.f);                        \
    } while (0)

#define PROC(rec) do {                                              \
      int sg_ = ((rec).x >> 16) & 63;                               \
      if (sg_ != curseg) { FLUSH_SEG(); curseg = sg_; }             \
    } while (0)

    for (; e + 3 < eend; e += 4) {
      int2 r0 = erec[e];
      int2 r1 = erec[e + 1];
      int2 r2 = erec[e + 2];
      int2 r3 = erec[e + 3];
      uint2 p0 = *(const uint2*)(XB + (size_t)(r0.x & 0xFFFF) * 512);
      uint2 p1 = *(const uint2*)(XB + (size_t)(r1.x & 0xFFFF) * 512);
      uint2 p2 = *(const uint2*)(XB + (size_t)(r2.x & 0xFFFF) * 512);
      uint2 p3 = *(const uint2*)(XB + (size_t)(r3.x & 0xFFFF) * 512);
      PROC(r0); fma4(acc, __int_as_float(r0.y), bf4_to_f4(p0));
      PROC(r1); fma4(acc, __int_as_float(r1.y), bf4_to_f4(p1));
      PROC(r2); fma4(acc, __int_as_float(r2.y), bf4_to_f4(p2));
      PROC(r3); fma4(acc, __int_as_float(r3.y), bf4_to_f4(p3));
    }
    for (; e < eend; ++e) {
      int2 r0 = erec[e];
      uint2 p0 = *(const uint2*)(XB + (size_t)(r0.x & 0xFFFF) * 512);
      PROC(r0); fma4(acc, __int_as_float(r0.y), bf4_to_f4(p0));
    }
    {
      float* dst_ = &acc_s[curseg * D + lane * 4];
      atomicAdd(dst_ + 0, acc.x); atomicAdd(dst_ + 1, acc.y);
      atomicAdd(dst_ + 2, acc.z); atomicAdd(dst_ + 3, acc.w);
    }
#undef PROC
#undef FLUSH_SEG
  }
  __syncthreads();

  // flush tile -> updx rows (stride 512 uints), cols 0..447 (bf16 pairs)
  const int nvalid = endn - b0;
#pragma unroll
  for (int i = 0; i < 14; ++i) {
    int idx = t + i * 256;            // 0..3583 over 8 x 448
    int node = idx / 448;
    int w448 = idx - node * 448;
    int rel = w448 >> 6;
    int k = (w448 * 2) & 127;
    if (node < nvalid) {
      float f0 = acc_s[((node << 3) | rel) * D + k];
      float f1 = acc_s[((node << 3) | rel) * D + k + 1];
      updx32[(size_t)(b0 + node) * 512 + w448] = pack_bf2(f0, f1);
    }
  }
}

// ---------- MFMA transform, register double-buffered ----------
// h = relu( updx(N x 1024 bf16) @ Wt^T + biases ).
// Block = 4 waves over 64 rows x 128 cols; wave = 32 rows x 64 cols
// (2 A-frags x 4 B-frags -> 8 MFMAs per K-chunk, 6 loads).
// Explicit double-buffer: prefetch chunk kc+32 while computing kc.
// Epilogue: intermediate layers write bf16 h into updx x-section; final
// layer writes fp32. __syncthreads() before epilogue (col-waves share rows).
__global__ __launch_bounds__(256) void xform_kernel(
    unsigned short* __restrict__ updx, const unsigned short* __restrict__ Wt,
    const float* __restrict__ brel, const float* __restrict__ bloop,
    float* __restrict__ hout, int n, int write_fp32) {
  const int t = threadIdx.x;
  const int w = t >> 6, lane = t & 63;
  const int rg = w >> 1, cg = w & 1;
  const int m0 = blockIdx.x * 64 + rg * 32;
  const int rt = lane & 15, quad = lane >> 4;

  const unsigned short* a0 = updx + (size_t)(m0 + rt) * KTOT + quad * 8;
  const unsigned short* a1 = a0 + (size_t)16 * KTOT;
  const unsigned short* b0 = Wt + (size_t)(cg * 64 + rt) * KTOT + quad * 8;
  const unsigned short* b1 = b0 + (size_t)16 * KTOT;
  const unsigned short* b2 = b0 + (size_t)32 * KTOT;
  const unsigned short* b3 = b0 + (size_t)48 * KTOT;

  f32x4 acc[2][4];
#pragma unroll
  for (int i = 0; i < 2; ++i)
#pragma unroll
    for (int c = 0; c < 4; ++c) acc[i][c] = (f32x4){0.f, 0.f, 0.f, 0.f};

  bf16x8 A0 = *(const bf16x8*)a0;
  bf16x8 A1 = *(const bf16x8*)a1;
  bf16x8 B0 = *(const bf16x8*)b0;
  bf16x8 B1 = *(const bf16x8*)b1;
  bf16x8 B2 = *(const bf16x8*)b2;
  bf16x8 B3 = *(const bf16x8*)b3;

  for (int kc = 32; kc <= KTOT; kc += 32) {
    // prefetch next chunk (last iteration reads 16B past the row: mapped ws)
    bf16x8 nA0 = *(const bf16x8*)(a0 + kc);
    bf16x8 nA1 = *(const bf16x8*)(a1 + kc);
    bf16x8 nB0 = *(const bf16x8*)(b0 + kc);
    bf16x8 nB1 = *(const bf16x8*)(b1 + kc);
    bf16x8 nB2 = *(const bf16x8*)(b2 + kc);
    bf16x8 nB3 = *(const bf16x8*)(b3 + kc);

    acc[0][0] = __builtin_amdgcn_mfma_f32_16x16x32_bf16(A0, B0, acc[0][0], 0, 0, 0);
    acc[0][1] = __builtin_amdgcn_mfma_f32_16x16x32_bf16(A0, B1, acc[0][1], 0, 0, 0);
    acc[0][2] = __builtin_amdgcn_mfma_f32_16x16x32_bf16(A0, B2, acc[0][2], 0, 0, 0);
    acc[0][3] = __builtin_amdgcn_mfma_f32_16x16x32_bf16(A0, B3, acc[0][3], 0, 0, 0);
    acc[1][0] = __builtin_amdgcn_mfma_f32_16x16x32_bf16(A1, B0, acc[1][0], 0, 0, 0);
    acc[1][1] = __builtin_amdgcn_mfma_f32_16x16x32_bf16(A1, B1, acc[1][1], 0, 0, 0);
    acc[1][2] = __builtin_amdgcn_mfma_f32_16x16x32_bf16(A1, B2, acc[1][2], 0, 0, 0);
    acc[1][3] = __builtin_amdgcn_mfma_f32_16x16x32_bf16(A1, B3, acc[1][3], 0, 0, 0);

    A0 = nA0; A1 = nA1;
    B0 = nB0; B1 = nB1; B2 = nB2; B3 = nB3;
  }

  __syncthreads();   // all K-reads in block done before x-section overwrite

  // C/D layout: col = lane&15, row = quad*4 + reg
#pragma unroll
  for (int rtile = 0; rtile < 2; ++rtile) {
#pragma unroll
    for (int cc = 0; cc < 4; ++cc) {
      int col = cg * 64 + cc * 16 + rt;
      float bias = brel[col] + bloop[col];
#pragma unroll
      for (int r = 0; r < 4; ++r) {
        int m = m0 + rtile * 16 + quad * 4 + r;
        if (m < n) {
          float v = fmaxf(acc[rtile][cc][r] + bias, 0.f);
          if (write_fp32) hout[(size_t)m * D + col] = v;
          else updx[(size_t)m * KTOT + 896 + col] = bf1(v);
        }
      }
    }
  }
}

// ---------- graph pooling (node2graph sorted) ----------
__global__ __launch_bounds__(256) void pool_kernel(const float* __restrict__ x,
    const int* __restrict__ n2g, float* __restrict__ gf, int n) {
  int d = threadIdx.x & 127;
  int sub = threadIdx.x >> 7;
  int n0 = (blockIdx.x * 2 + sub) * 128;
  int nend = n0 + 128;
  if (nend > n) nend = n;
  float acc = 0.f;
  int gcur = -1;
  for (int i = n0; i < nend; ++i) {
    int g = n2g[i];
    if (g != gcur) {
      if (gcur >= 0) atomicAdd(&gf[gcur * D + d], acc);
      gcur = g;
      acc = 0.f;
    }
    acc += x[(size_t)i * D + d];
  }
  if (gcur >= 0) atomicAdd(&gf[gcur * D + d], acc);
}

extern "C" void kernel_launch(void* const* d_in, const int* in_sizes, int n_in,
                              void* d_out, int out_size, void* d_ws, size_t ws_size,
                              hipStream_t stream) {
  const int*   unit_type  = (const int*)d_in[0];
  const int*   node_in    = (const int*)d_in[1];
  const int*   node_out   = (const int*)d_in[2];
  const int*   relation   = (const int*)d_in[3];
  const float* edge_w     = (const float*)d_in[4];
  const int*   node2graph = (const int*)d_in[5];
  const float* emb        = (const float*)d_in[6];
  const float* W_rel      = (const float*)d_in[7];
  const float* b_rel      = (const float*)d_in[8];
  const float* W_loop     = (const float*)d_in[9];
  const float* b_loop     = (const float*)d_in[10];

  const int n  = in_sizes[0];
  const int ne = in_sizes[1];
  float* out = (float*)d_out;

  const int nseg = n << SEG_SHIFT;
  const int nb   = (nseg + 1023) / 1024;

  // workspace layout
  unsigned short* updx     = (unsigned short*)d_ws;               // N x 1024 bf16
  unsigned short* Wt       = updx + (size_t)n * KTOT;             // 3 x 128 x 1024 bf16
  int2*           erec     = (int2*)(Wt + (size_t)LAYERS * D * KTOT);
  int*            hist     = (int*)(erec + ne);
  int*            row_ptr  = hist + nseg;
  int*            cursor   = row_ptr + ((nseg + 4) & ~3);
  int*            partials = cursor + nseg;

  hipMemsetAsync(d_out, 0, (size_t)GNUM * D * sizeof(float), stream);
  hipMemsetAsync(hist, 0, (size_t)nseg * sizeof(int), stream);

  const int eblocks = (ne + 255) / 256;
  hist_kernel<<<eblocks, 256, 0, stream>>>(node_out, relation, hist, ne);
  scan1_kernel<<<nb, 256, 0, stream>>>(hist, row_ptr, partials, nseg);
  scan2_kernel<<<1, 256, 0, stream>>>(partials, nb);
  scan3_kernel<<<(nseg + 255) / 256, 256, 0, stream>>>(row_ptr, cursor, partials, nseg, ne);
  fill_kernel<<<eblocks, 256, 0, stream>>>(node_in, node_out, relation, edge_w,
                                           cursor, erec, ne);

  wt_prep_kernel<<<(LAYERS * 128 * 512 + 255) / 256, 256, 0, stream>>>(
      W_rel, W_loop, (unsigned int*)Wt);

  initx_kernel<<<(n * 16 + 255) / 256, 256, 0, stream>>>(
      unit_type, emb, (unsigned int*)updx, n);

  const int ablocks = (n + NBA - 1) / NBA;
  const int tblocks = (n + 63) / 64;
  float* xfinal = out + GNUM * D;
  for (int i = 0; i < LAYERS; ++i) {
    agg_kernel<<<ablocks, 256, 0, stream>>>(erec, row_ptr,
                                            (unsigned int*)updx, n);
    xform_kernel<<<tblocks, 256, 0, stream>>>(
        updx, Wt + (size_t)i * D * KTOT,
        b_rel + (size_t)i * D, b_loop + (size_t)i * D,
        xfinal, n, (i == LAYERS - 1) ? 1 : 0);
  }

  pool_kernel<<<(n + 255) / 256, 256, 0, stream>>>(xfinal, node2graph, out, n);
}